// Round 12
// baseline (1982.579 us; speedup 1.0000x reference)
//
#include <hip/hip_runtime.h>
#include <hip/hip_bf16.h>

#define NSTEPS 64

typedef __attribute__((ext_vector_type(8))) short bf16x8;
typedef __attribute__((ext_vector_type(4))) float f32x4;

static __device__ __forceinline__ unsigned int cvtpk_bf16(float lo, float hi) {
  unsigned int d;
  asm("v_cvt_pk_bf16_f32 %0, %1, %2" : "=v"(d) : "v"(lo), "v"(hi));
  return d;
}

// Opaque 16B global load: asm-produced values cannot be rematerialized, so
// weight fragments stay RESIDENT (round 11: compiler banks them in AGPRs,
// no spill).  This is what finally defeats invariant-load remat.
static __device__ __forceinline__ bf16x8 gload16(const __hip_bfloat16* p) {
  bf16x8 r;
  asm volatile("global_load_dwordx4 %0, %1, off" : "=v"(r) : "v"(p));
  return r;
}

// ---------------------------------------------------------------------------
// prep (UNCHANGED, verified rounds 1/2/4/5/6/7/9/10/11): MFMA A-frags W1/W2.
// A1 frags: [mb=8][kc=5][lane=64][j=8] bf16, PERMUTED co:
//   co(mb, m) = (mb>>1)*32 + (m>>2)*8 + (mb&1)*4 + (m&3),  m = lane&15,
//   k = 32*kc + 8*(lane>>4) + j,  k = tap*16 + ci, zero for k>=144.
// GEMM1 acc of mb pair {2q,2q+1} IS the lane-exact GEMM2 B-fragment kc2=q.
// W2 frags at element 20480: [kc2=4][lane=64][j=8], natural k2 order.
// ---------------------------------------------------------------------------
__global__ void ca_prep(const float* __restrict__ w1, const float* __restrict__ w2,
                        __hip_bfloat16* __restrict__ fr) {
  int i = blockIdx.x * 256 + threadIdx.x;
  if (i < 20480) {
    int j  = i & 7;
    int l  = (i >> 3) & 63;
    int fi = i >> 9;          // mb*5 + kc
    int kc = fi % 5, mb = fi / 5;
    int m  = l & 15;
    int co = ((mb >> 1) << 5) + ((m >> 2) << 3) + ((mb & 1) << 2) + (m & 3);
    int k  = kc * 32 + ((l >> 4) << 3) + j;
    float v = 0.0f;
    if (k < 144) {
      int tap = k >> 4, ci = k & 15;
      v = w1[(co * 16 + ci) * 9 + tap];   // w1[co][ci][dy][dx], tap=dy*3+dx
    }
    fr[i] = __float2bfloat16(v);
  } else if (i < 22528) {
    int i2  = i - 20480;
    int j   = i2 & 7;
    int l   = (i2 >> 3) & 63;
    int kc2 = i2 >> 9;
    int k2  = kc2 * 32 + ((l >> 4) << 3) + j;
    fr[i] = __float2bfloat16(w2[(l & 15) * 128 + k2]);
  }
}

// ---------------------------------------------------------------------------
// one CA step — BARRIER-FREE main loop (round-2 dataflow + round-11 resident
// weights + round-6 NHWC layout; every piece individually verified).
//
// State mid-run: NHWC f32, elem = (b<<20)+(y<<12)+(x<<4)+c.
// Step 0 reads NCHW x; step 63 writes NCHW d_out.
//
// grid = 2048: b = bid&7 (batch->XCD), 16x16 grid of 16x16-px tiles.
// block = 256 threads = 4 waves.  Wave w owns rows {4w..4w+3} and ALL 8 mb:
// per row, GEMM1 acc[8] holds every GEMM2 B-fragment in-register (verified
// co-permutation), so relu+pack+GEMM2 need NO LDS staging and NO barriers.
// LDS b1-read traffic drops 4.8x vs the co-sliced rounds (each tile fragment
// read once per row, not once per wave); MFMA becomes the floor.
//
// Weights: 44 fragments (A1 8x5 + W2 4) via opaque loads, resident ~176 regs
// (AGPR-backed) -> 2 waves/SIMD, which is fine: waves are independent and
// latency-tolerant (no barrier-drain stalls).
//
// LDS (10368 B):  [0, 5184) h tile ci 0..7, [y=18][x=18] x 16B/pixel
//                 [5184, 10368) h tile ci 8..15, same
// ---------------------------------------------------------------------------
#define TILE0 0
#define TILE1 5184

template <bool IN_NCHW, bool OUT_NCHW>
__launch_bounds__(256, 2)
__global__ void ca_step(const float* __restrict__ hin,
                        float* __restrict__ hout,
                        const __hip_bfloat16* __restrict__ fr) {
  __shared__ __align__(16) char smem[10368];
  const int tid  = threadIdx.x;
  const int lane = tid & 63;
  const int w    = tid >> 6;          // 0..3
  const int bid  = blockIdx.x;
  const int b    = bid & 7;           // batch -> XCD round-robin
  const int t    = bid >> 3;          // 0..255
  const int ty   = t >> 4;            // 0..15
  const int tx   = t & 15;            // 0..15
  const int Y0   = ty << 4, X0 = tx << 4;
  const int ib   = b << 20;           // per-batch elems: 2^20 in BOTH layouts

  // ---- ALL weights resident via opaque loads: A1 8 mb x 5 kc + W2 ----
  bf16x8 a1r[8][5];
#pragma unroll
  for (int mb = 0; mb < 8; ++mb)
#pragma unroll
    for (int kc = 0; kc < 5; ++kc)
      a1r[mb][kc] = gload16(fr + (((mb * 5 + kc) * 64 + lane) << 3));
  bf16x8 w2f[4];
#pragma unroll
  for (int kc = 0; kc < 4; ++kc)
    w2f[kc] = gload16(fr + 20480 + ((kc * 64 + lane) << 3));
  asm volatile("s_waitcnt vmcnt(0)" ::: "memory");

  // ---- halo'd tile load: 18x18 px x 16 ch, f32 -> bf16 via cvt_pk ----
  for (int i = tid; i < 18 * 18; i += 256) {
    int y  = i / 18;
    int x  = i - y * 18;
    int GY = Y0 + y - 1, GX = X0 + x - 1;
    bool inb = ((unsigned)GY < 256u) && ((unsigned)GX < 256u);
    unsigned int pk[8];
    if (IN_NCHW) {
      int gof = ib + (GY << 8) + GX;
#pragma unroll
      for (int c = 0; c < 8; ++c) {
        float v0 = inb ? hin[gof + ((2 * c) << 16)] : 0.0f;
        float v1 = inb ? hin[gof + ((2 * c + 1) << 16)] : 0.0f;
        pk[c] = cvtpk_bf16(v0, v1);
      }
    } else {
      // NHWC: one 64 B record, 4x dwordx4, fully coalesced
      f32x4 q[4];
      if (inb) {
        const f32x4* rp = (const f32x4*)(hin + ib + (GY << 12) + (GX << 4));
#pragma unroll
        for (int qq = 0; qq < 4; ++qq) q[qq] = rp[qq];
      } else {
        const f32x4 z = {0.0f, 0.0f, 0.0f, 0.0f};
#pragma unroll
        for (int qq = 0; qq < 4; ++qq) q[qq] = z;
      }
#pragma unroll
      for (int c = 0; c < 8; ++c)
        pk[c] = cvtpk_bf16(q[c >> 1][(c & 1) * 2], q[c >> 1][(c & 1) * 2 + 1]);
    }
    *(uint4*)(smem + TILE0 + i * 16) = make_uint4(pk[0], pk[1], pk[2], pk[3]);
    *(uint4*)(smem + TILE1 + i * 16) = make_uint4(pk[4], pk[5], pk[6], pk[7]);
  }
  __syncthreads();   // the ONLY barrier: tile is read-only afterwards

  const int pix     = lane & 15;
  const int g       = lane >> 4;
  const int g1b     = g >> 1;                        // tap-select bit
  const int halfoff = (g & 1) ? TILE1 : TILE0;       // ci half

  const f32x4 z4 = {0.0f, 0.0f, 0.0f, 0.0f};

#pragma unroll 1
  for (int i = 0; i < 4; ++i) {
    const int row = (w << 2) + i;                    // wave w owns rows 4w..4w+3
    const int py  = Y0 + row;

    // hv prefetch: issue early, latency hides under GEMM1
    float hv[4];
    if (IN_NCHW) {
      const int gbB = ib + (py << 8) + X0 + pix;
#pragma unroll
      for (int r = 0; r < 4; ++r)
        hv[r] = hin[gbB + (((g << 2) + r) << 16)];
    } else {
      const f32x4 hvv =
          *(const f32x4*)(hin + ib + (py << 12) + ((X0 + pix) << 4) + (g << 2));
#pragma unroll
      for (int r = 0; r < 4; ++r) hv[r] = hvv[r];
    }

    // ---- GEMM1: all 8 mb for this row; one b1 read feeds 8 MFMAs ----
    f32x4 acc[8];
#pragma unroll
    for (int mb = 0; mb < 8; ++mb) acc[mb] = z4;

    const char* rowbase = smem + halfoff + (row * 18 + pix) * 16;
#pragma unroll
    for (int kc = 0; kc < 5; ++kc) {
      const int t0   = 2 * kc;
      const int t1   = (2 * kc + 1 > 8) ? 8 : 2 * kc + 1;  // tap 9 zero-pad
      const int off0 = ((t0 / 3) * 18 + (t0 % 3)) * 16;    // compile-time
      const int off1 = ((t1 / 3) * 18 + (t1 % 3)) * 16;
      const bf16x8 b1 = *(const bf16x8*)(rowbase + (g1b ? off1 : off0));
#pragma unroll
      for (int mb = 0; mb < 8; ++mb)
        acc[mb] = __builtin_amdgcn_mfma_f32_16x16x32_bf16(a1r[mb][kc], b1,
                                                          acc[mb], 0, 0, 0);
    }

    // ---- GEMM2 fully in-register (round-2-verified packing) ----
    f32x4 dxa = z4;
#pragma unroll
    for (int q = 0; q < 4; ++q) {
      const int me = 2 * q, mo = 2 * q + 1;
      union { unsigned int u[4]; bf16x8 v; } bb;
      bb.u[0] = cvtpk_bf16(fmaxf(acc[me][0], 0.0f), fmaxf(acc[me][1], 0.0f));
      bb.u[1] = cvtpk_bf16(fmaxf(acc[me][2], 0.0f), fmaxf(acc[me][3], 0.0f));
      bb.u[2] = cvtpk_bf16(fmaxf(acc[mo][0], 0.0f), fmaxf(acc[mo][1], 0.0f));
      bb.u[3] = cvtpk_bf16(fmaxf(acc[mo][2], 0.0f), fmaxf(acc[mo][3], 0.0f));
      dxa = __builtin_amdgcn_mfma_f32_16x16x32_bf16(w2f[q], bb.v, dxa, 0, 0, 0);
    }

    // ---- epilogue: h = clamp(h + dx) ----
    if (OUT_NCHW) {
      const int gbo = ib + (py << 8) + X0 + pix;
#pragma unroll
      for (int r = 0; r < 4; ++r) {
        const int co2 = (g << 2) + r;
        float v = hv[r] + dxa[r];
        const float lo = (co2 == 0) ? 0.0f : -3.0f;
        const float hi = (co2 == 0) ? 1.0f : 3.0f;
        v = fminf(fmaxf(v, lo), hi);
        hout[gbo + (co2 << 16)] = v;
      }
    } else {
      f32x4 ov;
#pragma unroll
      for (int r = 0; r < 4; ++r) {
        const int co2 = (g << 2) + r;
        float v = hv[r] + dxa[r];
        const float lo = (co2 == 0) ? 0.0f : -3.0f;
        const float hi = (co2 == 0) ? 1.0f : 3.0f;
        ov[r] = fminf(fmaxf(v, lo), hi);
      }
      *(f32x4*)(hout + ib + (py << 12) + ((X0 + pix) << 4) + (g << 2)) = ov;
    }
  }
}

// ---------------------------------------------------------------------------
extern "C" void kernel_launch(void* const* d_in, const int* in_sizes, int n_in,
                              void* d_out, int out_size, void* d_ws, size_t ws_size,
                              hipStream_t stream) {
  const float* x  = (const float*)d_in[0];
  const float* w1 = (const float*)d_in[1];
  const float* w2 = (const float*)d_in[2];
  float* out  = (float*)d_out;                  // NHWC scratch mid-run; NCHW at s=63
  float* ping = (float*)d_ws;                   // 33.5 MB NHWC state
  __hip_bfloat16* fr = (__hip_bfloat16*)((char*)d_ws + 33554432);

  ca_prep<<<88, 256, 0, stream>>>(w1, w2, fr);

  for (int s = 0; s < NSTEPS; ++s) {
    const float* in = (s == 0) ? x : ((s & 1) ? ping : out);
    float* o        = (s & 1) ? out : ping;     // s=63 (odd) -> d_out
    if (s == 0)
      ca_step<true, false><<<2048, 256, 0, stream>>>(in, o, fr);
    else if (s == NSTEPS - 1)
      ca_step<false, true><<<2048, 256, 0, stream>>>(in, o, fr);
    else
      ca_step<false, false><<<2048, 256, 0, stream>>>(in, o, fr);
  }
}

// Round 13
// 1733.610 us; speedup vs baseline: 1.1436x; 1.1436x over previous
//
#include <hip/hip_runtime.h>
#include <hip/hip_bf16.h>

#define NSTEPS 64

typedef __attribute__((ext_vector_type(8))) short bf16x8;
typedef __attribute__((ext_vector_type(4))) float f32x4;

static __device__ __forceinline__ unsigned int cvtpk_bf16(float lo, float hi) {
  unsigned int d;
  asm("v_cvt_pk_bf16_f32 %0, %1, %2" : "=v"(d) : "v"(lo), "v"(hi));
  return d;
}

// Opaque 16B global load: asm-produced values cannot be rematerialized, so
// weight fragments stay RESIDENT (round 11/12: no spill, AGPR-backed).
static __device__ __forceinline__ bf16x8 gload16(const __hip_bfloat16* p) {
  bf16x8 r;
  asm volatile("global_load_dwordx4 %0, %1, off" : "=v"(r) : "v"(p));
  return r;
}

// ---------------------------------------------------------------------------
// prep (UNCHANGED, verified rounds 1/2/4/5/6/7/9/10/11/12): MFMA A-frags.
// A1 frags: [mb=8][kc=5][lane=64][j=8] bf16, PERMUTED co:
//   co(mb, m) = (mb>>1)*32 + (m>>2)*8 + (mb&1)*4 + (m&3),  m = lane&15,
//   k = 32*kc + 8*(lane>>4) + j,  k = tap*16 + ci, zero for k>=144.
// GEMM1 acc of mb pair {2q,2q+1} IS the lane-exact GEMM2 B-fragment kc2=q.
// W2 frags at element 20480: [kc2=4][lane=64][j=8], natural k2 order.
// ---------------------------------------------------------------------------
__global__ void ca_prep(const float* __restrict__ w1, const float* __restrict__ w2,
                        __hip_bfloat16* __restrict__ fr) {
  int i = blockIdx.x * 256 + threadIdx.x;
  if (i < 20480) {
    int j  = i & 7;
    int l  = (i >> 3) & 63;
    int fi = i >> 9;          // mb*5 + kc
    int kc = fi % 5, mb = fi / 5;
    int m  = l & 15;
    int co = ((mb >> 1) << 5) + ((m >> 2) << 3) + ((mb & 1) << 2) + (m & 3);
    int k  = kc * 32 + ((l >> 4) << 3) + j;
    float v = 0.0f;
    if (k < 144) {
      int tap = k >> 4, ci = k & 15;
      v = w1[(co * 16 + ci) * 9 + tap];   // w1[co][ci][dy][dx], tap=dy*3+dx
    }
    fr[i] = __float2bfloat16(v);
  } else if (i < 22528) {
    int i2  = i - 20480;
    int j   = i2 & 7;
    int l   = (i2 >> 3) & 63;
    int kc2 = i2 >> 9;
    int k2  = kc2 * 32 + ((l >> 4) << 3) + j;
    fr[i] = __float2bfloat16(w2[(l & 15) * 128 + k2]);
  }
}

// ---------------------------------------------------------------------------
// one CA step — ROUND-12 INNER LOOP VERBATIM; geometry only changed:
// tiles 16 wide x 32 TALL, grid 1024 = exactly 4 blocks/CU (zero tail),
// 8 rows per wave.  Halves per-CU weight L2 traffic (the quantified
// invariant ~10.7 us across rounds 10-12) and halves prologue count.
//
// State mid-run: NHWC f32, elem = (b<<20)+(y<<12)+(x<<4)+c.
// Step 0 reads NCHW x; step 63 writes NCHW d_out.
//
// grid = 1024: b = bid&7 (batch->XCD), 16(x) x 8(y) grid of 16x32-px tiles.
// block = 256 threads = 4 waves.  Wave w owns rows {8w..8w+7}, ALL 8 mb:
// per row, GEMM1 acc[8] holds every GEMM2 B-fragment in-register (verified
// co-permutation) -> no staging, no barriers after tile load.
//
// LDS (19584 B): [0, 9792) h tile ci 0..7, [y=34][x=18] x 16B/pixel
//                [9792, 19584) h tile ci 8..15, same
// ---------------------------------------------------------------------------
#define TILE0 0
#define TILE1 9792

template <bool IN_NCHW, bool OUT_NCHW>
__launch_bounds__(256, 2)
__global__ void ca_step(const float* __restrict__ hin,
                        float* __restrict__ hout,
                        const __hip_bfloat16* __restrict__ fr) {
  __shared__ __align__(16) char smem[19584];
  const int tid  = threadIdx.x;
  const int lane = tid & 63;
  const int w    = tid >> 6;          // 0..3
  const int bid  = blockIdx.x;
  const int b    = bid & 7;           // batch -> XCD round-robin
  const int t    = bid >> 3;          // 0..127
  const int ty   = t >> 4;            // 0..7
  const int tx   = t & 15;            // 0..15
  const int Y0   = ty << 5, X0 = tx << 4;
  const int ib   = b << 20;           // per-batch elems: 2^20 in BOTH layouts

  // ---- ALL weights resident via opaque loads: A1 8 mb x 5 kc + W2 ----
  bf16x8 a1r[8][5];
#pragma unroll
  for (int mb = 0; mb < 8; ++mb)
#pragma unroll
    for (int kc = 0; kc < 5; ++kc)
      a1r[mb][kc] = gload16(fr + (((mb * 5 + kc) * 64 + lane) << 3));
  bf16x8 w2f[4];
#pragma unroll
  for (int kc = 0; kc < 4; ++kc)
    w2f[kc] = gload16(fr + 20480 + ((kc * 64 + lane) << 3));
  asm volatile("s_waitcnt vmcnt(0)" ::: "memory");

  // ---- halo'd tile load: 18 wide x 34 tall x 16 ch, f32 -> bf16 ----
  for (int i = tid; i < 18 * 34; i += 256) {
    int y  = i / 18;                  // 0..33
    int x  = i - y * 18;              // 0..17
    int GY = Y0 + y - 1, GX = X0 + x - 1;
    bool inb = ((unsigned)GY < 256u) && ((unsigned)GX < 256u);
    unsigned int pk[8];
    if (IN_NCHW) {
      int gof = ib + (GY << 8) + GX;
#pragma unroll
      for (int c = 0; c < 8; ++c) {
        float v0 = inb ? hin[gof + ((2 * c) << 16)] : 0.0f;
        float v1 = inb ? hin[gof + ((2 * c + 1) << 16)] : 0.0f;
        pk[c] = cvtpk_bf16(v0, v1);
      }
    } else {
      // NHWC: one 64 B record, 4x dwordx4, fully coalesced
      f32x4 q[4];
      if (inb) {
        const f32x4* rp = (const f32x4*)(hin + ib + (GY << 12) + (GX << 4));
#pragma unroll
        for (int qq = 0; qq < 4; ++qq) q[qq] = rp[qq];
      } else {
        const f32x4 z = {0.0f, 0.0f, 0.0f, 0.0f};
#pragma unroll
        for (int qq = 0; qq < 4; ++qq) q[qq] = z;
      }
#pragma unroll
      for (int c = 0; c < 8; ++c)
        pk[c] = cvtpk_bf16(q[c >> 1][(c & 1) * 2], q[c >> 1][(c & 1) * 2 + 1]);
    }
    *(uint4*)(smem + TILE0 + i * 16) = make_uint4(pk[0], pk[1], pk[2], pk[3]);
    *(uint4*)(smem + TILE1 + i * 16) = make_uint4(pk[4], pk[5], pk[6], pk[7]);
  }
  __syncthreads();   // the ONLY barrier: tile is read-only afterwards

  const int pix     = lane & 15;
  const int g       = lane >> 4;
  const int g1b     = g >> 1;                        // tap-select bit
  const int halfoff = (g & 1) ? TILE1 : TILE0;       // ci half

  const f32x4 z4 = {0.0f, 0.0f, 0.0f, 0.0f};

#pragma unroll 1
  for (int i = 0; i < 8; ++i) {
    const int row = (w << 3) + i;                    // wave w owns rows 8w..8w+7
    const int py  = Y0 + row;

    // hv prefetch: issue early, latency hides under GEMM1
    float hv[4];
    if (IN_NCHW) {
      const int gbB = ib + (py << 8) + X0 + pix;
#pragma unroll
      for (int r = 0; r < 4; ++r)
        hv[r] = hin[gbB + (((g << 2) + r) << 16)];
    } else {
      const f32x4 hvv =
          *(const f32x4*)(hin + ib + (py << 12) + ((X0 + pix) << 4) + (g << 2));
#pragma unroll
      for (int r = 0; r < 4; ++r) hv[r] = hvv[r];
    }

    // ---- GEMM1: all 8 mb for this row; one b1 read feeds 8 MFMAs ----
    f32x4 acc[8];
#pragma unroll
    for (int mb = 0; mb < 8; ++mb) acc[mb] = z4;

    const char* rowbase = smem + halfoff + (row * 18 + pix) * 16;
#pragma unroll
    for (int kc = 0; kc < 5; ++kc) {
      const int t0   = 2 * kc;
      const int t1   = (2 * kc + 1 > 8) ? 8 : 2 * kc + 1;  // tap 9 zero-pad
      const int off0 = ((t0 / 3) * 18 + (t0 % 3)) * 16;    // compile-time
      const int off1 = ((t1 / 3) * 18 + (t1 % 3)) * 16;
      const bf16x8 b1 = *(const bf16x8*)(rowbase + (g1b ? off1 : off0));
#pragma unroll
      for (int mb = 0; mb < 8; ++mb)
        acc[mb] = __builtin_amdgcn_mfma_f32_16x16x32_bf16(a1r[mb][kc], b1,
                                                          acc[mb], 0, 0, 0);
    }

    // ---- GEMM2 fully in-register (round-2-verified packing) ----
    f32x4 dxa = z4;
#pragma unroll
    for (int q = 0; q < 4; ++q) {
      const int me = 2 * q, mo = 2 * q + 1;
      union { unsigned int u[4]; bf16x8 v; } bb;
      bb.u[0] = cvtpk_bf16(fmaxf(acc[me][0], 0.0f), fmaxf(acc[me][1], 0.0f));
      bb.u[1] = cvtpk_bf16(fmaxf(acc[me][2], 0.0f), fmaxf(acc[me][3], 0.0f));
      bb.u[2] = cvtpk_bf16(fmaxf(acc[mo][0], 0.0f), fmaxf(acc[mo][1], 0.0f));
      bb.u[3] = cvtpk_bf16(fmaxf(acc[mo][2], 0.0f), fmaxf(acc[mo][3], 0.0f));
      dxa = __builtin_amdgcn_mfma_f32_16x16x32_bf16(w2f[q], bb.v, dxa, 0, 0, 0);
    }

    // ---- epilogue: h = clamp(h + dx) ----
    if (OUT_NCHW) {
      const int gbo = ib + (py << 8) + X0 + pix;
#pragma unroll
      for (int r = 0; r < 4; ++r) {
        const int co2 = (g << 2) + r;
        float v = hv[r] + dxa[r];
        const float lo = (co2 == 0) ? 0.0f : -3.0f;
        const float hi = (co2 == 0) ? 1.0f : 3.0f;
        v = fminf(fmaxf(v, lo), hi);
        hout[gbo + (co2 << 16)] = v;
      }
    } else {
      f32x4 ov;
#pragma unroll
      for (int r = 0; r < 4; ++r) {
        const int co2 = (g << 2) + r;
        float v = hv[r] + dxa[r];
        const float lo = (co2 == 0) ? 0.0f : -3.0f;
        const float hi = (co2 == 0) ? 1.0f : 3.0f;
        ov[r] = fminf(fmaxf(v, lo), hi);
      }
      *(f32x4*)(hout + ib + (py << 12) + ((X0 + pix) << 4) + (g << 2)) = ov;
    }
  }
}

// ---------------------------------------------------------------------------
extern "C" void kernel_launch(void* const* d_in, const int* in_sizes, int n_in,
                              void* d_out, int out_size, void* d_ws, size_t ws_size,
                              hipStream_t stream) {
  const float* x  = (const float*)d_in[0];
  const float* w1 = (const float*)d_in[1];
  const float* w2 = (const float*)d_in[2];
  float* out  = (float*)d_out;                  // NHWC scratch mid-run; NCHW at s=63
  float* ping = (float*)d_ws;                   // 33.5 MB NHWC state
  __hip_bfloat16* fr = (__hip_bfloat16*)((char*)d_ws + 33554432);

  ca_prep<<<88, 256, 0, stream>>>(w1, w2, fr);

  for (int s = 0; s < NSTEPS; ++s) {
    const float* in = (s == 0) ? x : ((s & 1) ? ping : out);
    float* o        = (s & 1) ? out : ping;     // s=63 (odd) -> d_out
    if (s == 0)
      ca_step<true, false><<<1024, 256, 0, stream>>>(in, o, fr);
    else if (s == NSTEPS - 1)
      ca_step<false, true><<<1024, 256, 0, stream>>>(in, o, fr);
    else
      ca_step<false, false><<<1024, 256, 0, stream>>>(in, o, fr);
  }
}